// Round 3
// baseline (732.085 us; speedup 1.0000x reference)
//
#include <hip/hip_runtime.h>
#include <hip/hip_bf16.h>

#define NN 50000
#define NPAD 50048   // pad so GEMM staging of the last M-block stays in-bounds
#define NR 8
#define NE 400000
#define CH 49        // ceil(NN/1024) scan chunks
// Blocked A layout: addr(n, col) = ((col>>5)*NPAD + n)*32 + (col&31)  [ushort elems]
#define SEGSTRIDE ((size_t)NPAD * 256)

typedef __attribute__((ext_vector_type(8))) short short8v;
typedef __attribute__((ext_vector_type(4))) float f32x4;

static __device__ __forceinline__ ushort f2b(float f) {
  union { float f; unsigned u; } v; v.f = f;
  unsigned u = v.u;
  unsigned r = (u + 0x7fffu + ((u >> 16) & 1u)) >> 16;
  return (ushort)r;
}
static __device__ __forceinline__ float b2f(ushort u) {
  union { unsigned u; float f; } v; v.u = ((unsigned)u) << 16;
  return v.f;
}

// ---------------- CSR build ----------------

__global__ __launch_bounds__(256) void k_hist(const int* __restrict__ dst,
                                              int* __restrict__ deg) {
  int e = blockIdx.x * 256 + threadIdx.x;
  int r = blockIdx.y;
  if (e < NE) atomicAdd(&deg[r * NN + dst[(size_t)r * NE + e]], 1);
}

// scan phase 1: per-1024-chunk sums
__global__ __launch_bounds__(1024) void k_scan1(const int* __restrict__ deg,
                                                int* __restrict__ csum) {
  int r = blockIdx.y, ch = blockIdx.x, t = threadIdx.x;
  int i = ch * 1024 + t;
  int v = (i < NN) ? deg[r * NN + i] : 0;
  #pragma unroll
  for (int o = 32; o; o >>= 1) v += __shfl_xor(v, o, 64);
  __shared__ int ws_[16];
  if ((t & 63) == 0) ws_[t >> 6] = v;
  __syncthreads();
  if (t < 16) {
    int s = ws_[t];
    #pragma unroll
    for (int o = 8; o; o >>= 1) s += __shfl_xor(s, o, 16);
    if (t == 0) csum[r * 64 + ch] = s;
  }
}

// scan phase 2: exclusive scan of 49 chunk sums per rel (1 wave per rel)
__global__ __launch_bounds__(512) void k_scan2(const int* __restrict__ csum,
                                               int* __restrict__ cbase) {
  int w = threadIdx.x >> 6, l = threadIdx.x & 63;
  int v = (l < CH) ? csum[w * 64 + l] : 0;
  int s = v;
  #pragma unroll
  for (int o = 1; o < 64; o <<= 1) {
    int u = __shfl_up(s, o, 64);
    if (l >= o) s += u;
  }
  if (l < CH) cbase[w * 64 + l] = s - v;
}

// scan phase 3: per-chunk exclusive scan + chunk base
__global__ __launch_bounds__(1024) void k_scan3(const int* __restrict__ deg,
                                                const int* __restrict__ cbase,
                                                int* __restrict__ offs) {
  int r = blockIdx.y, ch = blockIdx.x, t = threadIdx.x;
  int lane = t & 63, w = t >> 6;
  __shared__ int wsum[16];
  int i = ch * 1024 + t;
  int v = (i < NN) ? deg[r * NN + i] : 0;
  int s = v;
  #pragma unroll
  for (int o = 1; o < 64; o <<= 1) {
    int u = __shfl_up(s, o, 64);
    if (lane >= o) s += u;
  }
  if (lane == 63) wsum[w] = s;
  __syncthreads();
  int wbase = 0;
  #pragma unroll
  for (int k2 = 0; k2 < 16; ++k2) wbase += (k2 < w) ? wsum[k2] : 0;
  if (i < NN) offs[r * NN + i] = cbase[r * 64 + ch] + wbase + (s - v);
}

__global__ __launch_bounds__(256) void k_fill(const int* __restrict__ src,
                                              const int* __restrict__ dst,
                                              const int* __restrict__ offs,
                                              int* __restrict__ cur,
                                              int* __restrict__ csr) {
  int e = blockIdx.x * 256 + threadIdx.x;
  int r = blockIdx.y;
  if (e >= NE) return;
  int d = dst[(size_t)r * NE + e];
  int p = offs[r * NN + d] + atomicAdd(&cur[r * NN + d], 1);
  csr[(size_t)r * NE + p] = src[(size_t)r * NE + e];
}

// ---------------- x -> bf16, column-blocked [chunk][n][32] ----------------

__global__ __launch_bounds__(256) void k_xconv(const float* __restrict__ x,
                                               ushort* __restrict__ xbc) {
  int i = blockIdx.x * 256 + threadIdx.x;  // one float4 per thread
  if (i >= NN * 64) return;
  int n = i >> 6, q = i & 63;  // cols q*4 .. q*4+3
  float4 v = ((const float4*)x)[i];
  ushort4 o;
  o.x = f2b(v.x); o.y = f2b(v.y); o.z = f2b(v.z); o.w = f2b(v.w);
  *(ushort4*)(xbc + ((size_t)(q >> 3) * NPAD + n) * 32 + (q & 7) * 4) = o;
}

// ---------------- weights -> bf16, transposed [seg][n][k] ----------------

__global__ __launch_bounds__(256) void k_wconv(const float* __restrict__ w,
                                               const float* __restrict__ lw,
                                               ushort* __restrict__ wb) {
  int i = blockIdx.x * 256 + threadIdx.x;
  if (i >= 9 * 65536) return;
  int s = i >> 16, rem = i & 65535, k = rem >> 8, n = rem & 255;
  float v = (s < 8) ? w[(size_t)s * 65536 + k * 256 + n] : lw[k * 256 + n];
  wb[(size_t)s * 65536 + (size_t)n * 256 + k] = f2b(v);
}

// ---------------- aggregation: 8-lane group per (node, rel, chunk) ----------------
// Gathers 64 B chunk rows from L2-resident xbc chunk (3.2 MB); chunk = blockIdx.z
// is the slowest grid dim so all concurrently-resident blocks share one chunk.

__global__ __launch_bounds__(256) void k_agg(const ushort* __restrict__ xbc,
                                             const int* __restrict__ csr,
                                             const int* __restrict__ offs,
                                             const int* __restrict__ deg,
                                             ushort* __restrict__ xa,
                                             long strideR, int r0) {
  int t = threadIdx.x;
  int wid = t >> 6, lane = t & 63;
  int gid = lane >> 3, gl = lane & 7;
  int n = blockIdx.x * 32 + wid * 8 + gid;
  int r = r0 + blockIdx.y;
  int c = blockIdx.z;
  if (n >= NN) return;
  int base = offs[r * NN + n];
  int dg = deg[r * NN + n];
  const int* lst = csr + (size_t)r * NE + base;
  const ushort* xc = xbc + (size_t)c * NPAD * 32;
  float a0 = 0.f, a1 = 0.f, a2 = 0.f, a3 = 0.f;
  int j = 0;
  for (; j + 1 < dg; j += 2) {
    int s0 = lst[j], s1 = lst[j + 1];
    ushort4 v0 = *(const ushort4*)(xc + (size_t)s0 * 32 + gl * 4);
    ushort4 v1 = *(const ushort4*)(xc + (size_t)s1 * 32 + gl * 4);
    a0 += b2f(v0.x) + b2f(v1.x);
    a1 += b2f(v0.y) + b2f(v1.y);
    a2 += b2f(v0.z) + b2f(v1.z);
    a3 += b2f(v0.w) + b2f(v1.w);
  }
  if (j < dg) {
    ushort4 v0 = *(const ushort4*)(xc + (size_t)lst[j] * 32 + gl * 4);
    a0 += b2f(v0.x); a1 += b2f(v0.y); a2 += b2f(v0.z); a3 += b2f(v0.w);
  }
  float inv = 1.f / (float)max(dg, 1);
  ushort4 o;
  o.x = f2b(a0 * inv); o.y = f2b(a1 * inv); o.z = f2b(a2 * inv); o.w = f2b(a3 * inv);
  *(ushort4*)(xa + (size_t)(r - r0) * strideR + ((size_t)c * NPAD + n) * 32 + gl * 4) = o;
}

// ---------------- GEMM (m97-style): out[M,256] (+)= sum_s A_s[M,256] @ W_s ----------------
// A_s blocked layout; seg 8's A is xbc itself. W [n][k] bf16.

#define BM 128
#define BN 128
#define BK 64

__global__ __launch_bounds__(256) void k_gemm(const ushort* __restrict__ xa, long strideR,
                                              int nseg, const ushort* __restrict__ xbc,
                                              const ushort* __restrict__ wb, int wseg0,
                                              const float* __restrict__ bias,
                                              float* __restrict__ out, int first, int final_) {
  __shared__ ushort As[BM * BK];
  __shared__ ushort Bs[BN * BK];
  int t = threadIdx.x;
  int lane = t & 63, wid = t >> 6;
  int wm = wid >> 1, wn = wid & 1;
  int i0 = blockIdx.x * BM, n0 = blockIdx.y * BN;

  f32x4 acc[4][4];
  #pragma unroll
  for (int a = 0; a < 4; ++a)
    #pragma unroll
    for (int b = 0; b < 4; ++b) acc[a][b] = (f32x4){0.f, 0.f, 0.f, 0.f};

  for (int s = 0; s < nseg; ++s) {
    const ushort* A = (wseg0 + s < 8) ? (xa + (size_t)s * strideR) : xbc;
    const ushort* W = wb + (size_t)(wseg0 + s) * 65536;
    for (int kt = 0; kt < 256; kt += BK) {
      __syncthreads();
      #pragma unroll
      for (int it = 0; it < 4; ++it) {
        int flat = it * 256 + t;
        int row = flat >> 3, sg = flat & 7;
        int col = kt + sg * 8;
        const ushort* ga = A + ((size_t)(col >> 5) * NPAD + (i0 + row)) * 32 + (col & 31);
        __builtin_amdgcn_global_load_lds(
            (const __attribute__((address_space(1))) unsigned int*)ga,
            (__attribute__((address_space(3))) unsigned int*)(As + flat * 8), 16, 0, 0);
      }
      #pragma unroll
      for (int it = 0; it < 4; ++it) {
        int flat = it * 256 + t;
        int row = flat >> 3, sg = flat & 7;
        const ushort* gb = W + (size_t)(n0 + row) * 256 + kt + sg * 8;
        __builtin_amdgcn_global_load_lds(
            (const __attribute__((address_space(1))) unsigned int*)gb,
            (__attribute__((address_space(3))) unsigned int*)(Bs + flat * 8), 16, 0, 0);
      }
      __syncthreads();
      #pragma unroll
      for (int kk = 0; kk < 2; ++kk) {
        int ko = kk * 32 + (lane >> 4) * 8;
        short8v a_frag[4], b_frag[4];
        #pragma unroll
        for (int mi = 0; mi < 4; ++mi)
          a_frag[mi] = *(const short8v*)(As + (wm * 64 + mi * 16 + (lane & 15)) * BK + ko);
        #pragma unroll
        for (int ni = 0; ni < 4; ++ni)
          b_frag[ni] = *(const short8v*)(Bs + (wn * 64 + ni * 16 + (lane & 15)) * BK + ko);
        #pragma unroll
        for (int mi = 0; mi < 4; ++mi)
          #pragma unroll
          for (int ni = 0; ni < 4; ++ni)
            acc[mi][ni] = __builtin_amdgcn_mfma_f32_16x16x32_bf16(
                a_frag[mi], b_frag[ni], acc[mi][ni], 0, 0, 0);
      }
    }
  }

  // epilogue: C elem (col = lane&15, row = (lane>>4)*4 + reg)
  #pragma unroll
  for (int mi = 0; mi < 4; ++mi) {
    int rbase = i0 + wm * 64 + mi * 16 + ((lane >> 4) << 2);
    #pragma unroll
    for (int ni = 0; ni < 4; ++ni) {
      int col = n0 + wn * 64 + ni * 16 + (lane & 15);
      float bv = final_ ? bias[col] : 0.f;
      #pragma unroll
      for (int rg = 0; rg < 4; ++rg) {
        int gm = rbase + rg;
        if (gm < NN) {
          size_t o = (size_t)gm * 256 + col;
          float v = acc[mi][ni][rg];
          if (!first) v += out[o];
          if (final_) v = fmaxf(v + bv, 0.f);
          out[o] = v;
        }
      }
    }
  }
}

// ---------------- host ----------------

extern "C" void kernel_launch(void* const* d_in, const int* in_sizes, int n_in,
                              void* d_out, int out_size, void* d_ws, size_t ws_size,
                              hipStream_t stream) {
  const float* x = (const float*)d_in[0];
  const float* w = (const float*)d_in[1];
  const float* bias = (const float*)d_in[2];
  const float* lw = (const float*)d_in[3];
  const int* src = (const int*)d_in[4];
  const int* dst = (const int*)d_in[5];
  float* out = (float*)d_out;

  char* ws = (char*)d_ws;
  size_t off = 0;
  auto carve = [&](size_t bytes) {
    size_t o = off;
    off = (off + bytes + 255) & ~(size_t)255;
    return o;
  };
  int* deg = (int*)(ws + carve((size_t)NR * NN * 4));
  int* offs = (int*)(ws + carve((size_t)NR * NN * 4));
  int* csr = (int*)(ws + carve((size_t)NR * NE * 4));
  ushort* wb = (ushort*)(ws + carve((size_t)9 * 65536 * 2));
  int* csum = (int*)(ws + carve((size_t)8 * 64 * 4));
  int* cbase = (int*)(ws + carve((size_t)8 * 64 * 4));
  ushort* xbc = (ushort*)(ws + carve(SEGSTRIDE * 2));
  size_t base_bytes = off;
  ushort* xa = (ushort*)(ws + off);
  // cur[] overlays xa region: cur is dead after k_fill, xa written after.
  int* cur = (int*)(ws + off);
  bool full = (ws_size >= base_bytes + (size_t)NR * SEGSTRIDE * 2);

  hipMemsetAsync(deg, 0, (size_t)NR * NN * 4, stream);
  hipMemsetAsync(cur, 0, (size_t)NR * NN * 4, stream);
  dim3 egrid((NE + 255) / 256, NR);
  k_hist<<<egrid, 256, 0, stream>>>(dst, deg);
  k_scan1<<<dim3(CH, NR), 1024, 0, stream>>>(deg, csum);
  k_scan2<<<1, 512, 0, stream>>>(csum, cbase);
  k_scan3<<<dim3(CH, NR), 1024, 0, stream>>>(deg, cbase, offs);
  k_fill<<<egrid, 256, 0, stream>>>(src, dst, offs, cur, csr);
  k_xconv<<<(NN * 64 + 255) / 256, 256, 0, stream>>>(x, xbc);
  k_wconv<<<(9 * 65536 + 255) / 256, 256, 0, stream>>>(w, lw, wb);

  dim3 agg_grid((NN + 31) / 32, NR, 8);
  dim3 gemm_grid((NN + BM - 1) / BM, 256 / BN);
  if (full) {
    k_agg<<<agg_grid, 256, 0, stream>>>(xbc, csr, offs, deg, xa, (long)SEGSTRIDE, 0);
    k_gemm<<<gemm_grid, 256, 0, stream>>>(xa, (long)SEGSTRIDE, 9, xbc, wb, 0, bias, out, 1, 1);
  } else {
    // fallback: one relation at a time reusing a single xa segment
    for (int r = 0; r < 8; ++r) {
      k_agg<<<dim3((NN + 31) / 32, 1, 8), 256, 0, stream>>>(xbc, csr, offs, deg, xa, 0, r);
      k_gemm<<<gemm_grid, 256, 0, stream>>>(xa, 0, 1, xbc, wb, r, bias, out,
                                            (r == 0) ? 1 : 0, 0);
    }
    k_gemm<<<gemm_grid, 256, 0, stream>>>(xa, 0, 1, xbc, wb, 8, bias, out, 0, 1);
  }
  (void)in_sizes; (void)n_in; (void)out_size;
}